// Round 4
// baseline (196.067 us; speedup 1.0000x reference)
//
#include <hip/hip_runtime.h>
#include <hip/hip_bf16.h>

#define N_NODES 50000
#define N_PAD   50048   // 391 * 128
#define N_EDGES 150000
#define F 512
#define BM 128
#define BN 128
#define BK 64
#define NBLK 196        // ceil(50000/256)
#define NWG  1564       // 391 * 4 gemm blocks

typedef __attribute__((ext_vector_type(4))) float f32x4;
typedef __attribute__((ext_vector_type(4))) unsigned int u32x4;
typedef __attribute__((ext_vector_type(2))) unsigned int u32x2;

__device__ __forceinline__ unsigned short f2bf(float f) {
    unsigned int u = __float_as_uint(f);
    return (unsigned short)((u + 0x7fffu + ((u >> 16) & 1u)) >> 16);
}
__device__ __forceinline__ unsigned int pack2(float a, float b) {
    return (unsigned int)f2bf(a) | ((unsigned int)f2bf(b) << 16);
}
__device__ __forceinline__ void gload16(const void* g, void* l) {
    __builtin_amdgcn_global_load_lds(
        (const __attribute__((address_space(1))) unsigned int*)g,
        (__attribute__((address_space(3))) unsigned int*)l, 16, 0, 0);
}

// ---- degree histograms ----
__global__ void __launch_bounds__(256) crd_deg(const int* __restrict__ src,
                                               const int* __restrict__ dst,
                                               int* __restrict__ hist) {
    int e = blockIdx.x * 256 + threadIdx.x;
    if (e < N_EDGES) {
        atomicAdd(&hist[src[e]], 1);
        atomicAdd(&hist[N_NODES + dst[e]], 1);
    }
}

__global__ void __launch_bounds__(256) crd_norm(const int* __restrict__ hist,
                                                float* __restrict__ norms) {
    int i = blockIdx.x * 256 + threadIdx.x;
    if (i < 2 * N_NODES) {
        int d = hist[i];
        norms[i] = rsqrtf((float)(d > 0 ? d : 1));
    }
}

// ---- hierarchical exclusive scan of deg_in ----
__global__ void __launch_bounds__(256) crd_bsum(const int* __restrict__ hist_in,
                                                int* __restrict__ bsum) {
    __shared__ int s[256];
    int t = threadIdx.x;
    int i = blockIdx.x * 256 + t;
    s[t] = (i < N_NODES) ? hist_in[i] : 0;
    __syncthreads();
    #pragma unroll
    for (int o = 128; o > 0; o >>= 1) {
        if (t < o) s[t] += s[t + o];
        __syncthreads();
    }
    if (t == 0) bsum[blockIdx.x] = s[0];
}

__global__ void __launch_bounds__(256) crd_bscan(const int* __restrict__ bsum,
                                                 int* __restrict__ bsumoff) {
    __shared__ int s[256];
    int t = threadIdx.x;
    int v = (t < NBLK) ? bsum[t] : 0;
    s[t] = v;
    __syncthreads();
    #pragma unroll
    for (int d = 1; d < 256; d <<= 1) {
        int add = (t >= d) ? s[t - d] : 0;
        __syncthreads();
        s[t] += add;
        __syncthreads();
    }
    if (t < NBLK) bsumoff[t] = s[t] - v;
}

__global__ void __launch_bounds__(256) crd_escan(const int* __restrict__ hist_in,
                                                 const int* __restrict__ bsumoff,
                                                 int* __restrict__ off,
                                                 int* __restrict__ cursor) {
    __shared__ int s[256];
    int t = threadIdx.x;
    int i = blockIdx.x * 256 + t;
    int v = (i < N_NODES) ? hist_in[i] : 0;
    s[t] = v;
    __syncthreads();
    #pragma unroll
    for (int d = 1; d < 256; d <<= 1) {
        int add = (t >= d) ? s[t - d] : 0;
        __syncthreads();
        s[t] += add;
        __syncthreads();
    }
    int excl = s[t] - v + bsumoff[blockIdx.x];
    if (i < N_NODES) { off[i] = excl; cursor[i] = excl; }
    if (i == N_NODES - 1) off[N_NODES] = excl + v;
}

__global__ void __launch_bounds__(256) crd_place(const int* __restrict__ src,
                                                 const int* __restrict__ dst,
                                                 int* __restrict__ cursor,
                                                 int* __restrict__ sorted) {
    int e = blockIdx.x * 256 + threadIdx.x;
    if (e < N_EDGES) {
        int slot = atomicAdd(&cursor[dst[e]], 1);
        sorted[slot] = src[e];
    }
}

__global__ void __launch_bounds__(256) crd_wt(const float* __restrict__ W,
                                              unsigned short* __restrict__ Wt) {
    int idx = blockIdx.x * 256 + threadIdx.x;
    int n = idx >> 9, k = idx & 511;
    Wt[idx] = f2bf(W[k * F + n]);
}

// ---- xb = bf16(x * norm_src), 8 elems/thread ----
__global__ void __launch_bounds__(256) crd_xb(const float* __restrict__ x,
                                              const float* __restrict__ norms,
                                              unsigned short* __restrict__ xb) {
    int t = blockIdx.x * 256 + threadIdx.x;        // 3.2M threads
    size_t i = (size_t)t * 8;
    float ns = norms[t >> 6];                      // 64 threads per 512-row
    f32x4 v0 = *(const f32x4*)(x + i);
    f32x4 v1 = *(const f32x4*)(x + i + 4);
    v0 *= ns; v1 *= ns;
    u32x4 w;
    w.x = pack2(v0.x, v0.y); w.y = pack2(v0.z, v0.w);
    w.z = pack2(v1.x, v1.y); w.w = pack2(v1.z, v1.w);
    *(u32x4*)(xb + i) = w;
}

__device__ __forceinline__ void acc8(float* a, u32x4 v) {
    a[0] += __uint_as_float(v.x << 16); a[1] += __uint_as_float(v.x & 0xffff0000u);
    a[2] += __uint_as_float(v.y << 16); a[3] += __uint_as_float(v.y & 0xffff0000u);
    a[4] += __uint_as_float(v.z << 16); a[5] += __uint_as_float(v.z & 0xffff0000u);
    a[6] += __uint_as_float(v.w << 16); a[7] += __uint_as_float(v.w & 0xffff0000u);
}

// ---- one wave per dst node; xb already has norm_src folded in ----
__global__ void __launch_bounds__(256) crd_gather_bf(const unsigned short* __restrict__ xb,
                                                     const int* __restrict__ sorted,
                                                     const int* __restrict__ off,
                                                     const float* __restrict__ norms,
                                                     unsigned short* __restrict__ aggb) {
    int wid = (blockIdx.x * 256 + threadIdx.x) >> 6;
    int lane = threadIdx.x & 63;
    if (wid >= N_PAD) return;
    float a[8] = {0.f,0.f,0.f,0.f,0.f,0.f,0.f,0.f};
    float b[8] = {0.f,0.f,0.f,0.f,0.f,0.f,0.f,0.f};
    if (wid < N_NODES) {
        int e0 = off[wid], e1 = off[wid + 1];
        int e = e0;
        for (; e + 1 < e1; e += 2) {
            int s0 = sorted[e], s1 = sorted[e + 1];
            u32x4 v0 = *(const u32x4*)(xb + (size_t)s0 * F + lane * 8);
            u32x4 v1 = *(const u32x4*)(xb + (size_t)s1 * F + lane * 8);
            acc8(a, v0);
            acc8(b, v1);
        }
        if (e < e1) {
            u32x4 v0 = *(const u32x4*)(xb + (size_t)sorted[e] * F + lane * 8);
            acc8(a, v0);
        }
        float nd = norms[N_NODES + wid];
        #pragma unroll
        for (int j = 0; j < 8; ++j) a[j] = (a[j] + b[j]) * nd;
    }
    u32x4 w;
    w.x = pack2(a[0], a[1]); w.y = pack2(a[2], a[3]);
    w.z = pack2(a[4], a[5]); w.w = pack2(a[6], a[7]);
    *(u32x4*)(aggb + (size_t)wid * F + lane * 8) = w;
}

// ---- fallback (ws too small for xb): f32 x path ----
__global__ void __launch_bounds__(256) crd_gather_f32(const float* __restrict__ x,
                                                      const int* __restrict__ sorted,
                                                      const int* __restrict__ off,
                                                      const float* __restrict__ norms,
                                                      unsigned short* __restrict__ aggb) {
    int wid = (blockIdx.x * 256 + threadIdx.x) >> 6;
    int lane = threadIdx.x & 63;
    if (wid >= N_PAD) return;
    f32x4 a0 = {0.f,0.f,0.f,0.f}, a1 = a0;
    if (wid < N_NODES) {
        int e0 = off[wid], e1 = off[wid + 1];
        for (int e = e0; e < e1; ++e) {
            int s = sorted[e];
            float ns = norms[s];
            const f32x4* p = (const f32x4*)(x + (size_t)s * F);
            a0 += p[lane] * ns;
            a1 += p[64 + lane] * ns;
        }
        float nd = norms[N_NODES + wid];
        a0 *= nd; a1 *= nd;
    }
    unsigned short* row = aggb + (size_t)wid * F;
    u32x2 w0, w1;
    w0.x = pack2(a0.x, a0.y); w0.y = pack2(a0.z, a0.w);
    w1.x = pack2(a1.x, a1.y); w1.y = pack2(a1.z, a1.w);
    *(u32x2*)(row + lane * 4) = w0;
    *(u32x2*)(row + 256 + lane * 4) = w1;
}

// ---- out = relu(aggb @ W + b): 2-phase double-buffered bf16 MFMA ----
__global__ void __launch_bounds__(256, 2) crd_gemm(const unsigned short* __restrict__ aggb,
                                                   const unsigned short* __restrict__ Wt,
                                                   const float* __restrict__ bias,
                                                   float* __restrict__ out) {
    __shared__ __align__(16) unsigned short lA[2][8 * BM * 8];   // 2 x 16 KB
    __shared__ __align__(16) unsigned short lB[2][8 * BN * 8];   // 2 x 16 KB
    const int tid = threadIdx.x;
    // XCD-bijective swizzle (m204): nwg=1564, q=195, r=4; n-minor decode so the
    // 4 blocks sharing an A-panel are swz-consecutive -> same XCD L2.
    int bid = blockIdx.x;
    int xcd = bid & 7, lid = bid >> 3;
    int swz = (xcd < 4 ? xcd * 196 : 784 + (xcd - 4) * 195) + lid;
    const int rowbase = (swz >> 2) * BM;
    const int nbase = (swz & 3) * BN;
    const int lane = tid & 63;
    const int wave = tid >> 6;
    const int wm = wave >> 1, wn = wave & 1;
    const int g = lane >> 4, r = lane & 15;

    f32x4 zero4 = {0.f, 0.f, 0.f, 0.f};
    f32x4 acc[4][4];
    #pragma unroll
    for (int i = 0; i < 4; ++i)
        #pragma unroll
        for (int j = 0; j < 4; ++j) acc[i][j] = zero4;

#define STAGE(B, KS) do { \
    _Pragma("unroll") \
    for (int j_ = 0; j_ < 4; ++j_) { \
        int gg = (wave * 4 + j_) * 64 + lane; \
        int k8 = gg >> 7, rw = gg & 127; \
        gload16(aggb + (size_t)(rowbase + rw) * F + (KS) * BK + k8 * 8, \
                &lA[B][(wave * 4 + j_) * 512]); \
    } \
    _Pragma("unroll") \
    for (int j_ = 0; j_ < 4; ++j_) { \
        int gg = (wave * 4 + j_) * 64 + lane; \
        int k8 = gg >> 7, nn = gg & 127; \
        gload16(Wt + (size_t)(nbase + nn) * F + (KS) * BK + k8 * 8, \
                &lB[B][(wave * 4 + j_) * 512]); \
    } \
} while (0)

#define COMPUTE(B) do { \
    _Pragma("unroll") \
    for (int kk = 0; kk < 2; ++kk) { \
        int k8 = kk * 4 + g; \
        u32x4 af[4], bfr[4]; \
        _Pragma("unroll") \
        for (int mi = 0; mi < 4; ++mi) \
            af[mi] = *(const u32x4*)&lA[B][(k8 * BM + wm * 64 + mi * 16 + r) * 8]; \
        _Pragma("unroll") \
        for (int ni = 0; ni < 4; ++ni) \
            bfr[ni] = *(const u32x4*)&lB[B][(k8 * BN + wn * 64 + ni * 16 + r) * 8]; \
        _Pragma("unroll") \
        for (int mi = 0; mi < 4; ++mi) \
            _Pragma("unroll") \
            for (int ni = 0; ni < 4; ++ni) \
                asm("v_mfma_f32_16x16x32_bf16 %0, %1, %2, %0" \
                    : "+v"(acc[mi][ni]) : "v"(af[mi]), "v"(bfr[ni])); \
    } \
} while (0)

    STAGE(0, 0);
    __syncthreads();
    #pragma unroll
    for (int ks2 = 0; ks2 < 4; ++ks2) {
        STAGE(1, 2 * ks2 + 1);       // prefetch odd tile while computing even
        COMPUTE(0);
        __syncthreads();             // vmcnt(0) drain lands after compute hid it
        if (ks2 < 3) STAGE(0, 2 * ks2 + 2);
        COMPUTE(1);
        __syncthreads();
    }
#undef STAGE
#undef COMPUTE

    #pragma unroll
    for (int ni = 0; ni < 4; ++ni) {
        int col = nbase + wn * 64 + ni * 16 + r;
        float bv = bias[col];
        #pragma unroll
        for (int mi = 0; mi < 4; ++mi) {
            #pragma unroll
            for (int j = 0; j < 4; ++j) {
                int row = rowbase + wm * 64 + mi * 16 + g * 4 + j;
                if (row < N_NODES) {
                    float v = acc[mi][ni][j] + bv;
                    out[(size_t)row * F + col] = v > 0.0f ? v : 0.0f;
                }
            }
        }
    }
}

extern "C" void kernel_launch(void* const* d_in, const int* in_sizes, int n_in,
                              void* d_out, int out_size, void* d_ws, size_t ws_size,
                              hipStream_t stream) {
    const float* x = (const float*)d_in[0];
    const int* src = (const int*)d_in[1];
    const int* dst = (const int*)d_in[2];
    const float* W = (const float*)d_in[3];
    const float* bias = (const float*)d_in[4];
    float* out = (float*)d_out;

    unsigned short* aggb = (unsigned short*)d_ws;               // N_PAD*F bf16
    unsigned short* Wt = aggb + (size_t)N_PAD * F;              // F*F bf16
    float* norms = (float*)(Wt + (size_t)F * F);                // 2N f32
    int* hist = (int*)(norms + 2 * N_NODES);                    // 2N int
    int* off = hist + 2 * N_NODES;                              // N+1 int
    int* cursor = off + N_NODES + 1;                            // N int
    int* sorted = cursor + N_NODES;                             // E int
    int* bsum = sorted + N_EDGES;                               // NBLK int
    int* bsumoff = bsum + NBLK;                                 // NBLK int
    char* endp = (char*)(bsumoff + NBLK);
    unsigned short* xb = (unsigned short*)(((uintptr_t)endp + 63) & ~(uintptr_t)63);
    size_t need_min = (size_t)(endp - (char*)d_ws);
    size_t need_bf = (size_t)((char*)(xb + (size_t)N_NODES * F) - (char*)d_ws);
    if (ws_size < need_min) {
        hipMemsetAsync(d_out, 0, (size_t)out_size * sizeof(float), stream);
        return;
    }
    const bool use_bf = (ws_size >= need_bf);

    hipMemsetAsync(hist, 0, 2 * N_NODES * sizeof(int), stream);
    crd_deg<<<(N_EDGES + 255) / 256, 256, 0, stream>>>(src, dst, hist);
    crd_norm<<<(2 * N_NODES + 255) / 256, 256, 0, stream>>>(hist, norms);
    crd_bsum<<<NBLK, 256, 0, stream>>>(hist + N_NODES, bsum);
    crd_bscan<<<1, 256, 0, stream>>>(bsum, bsumoff);
    crd_escan<<<NBLK, 256, 0, stream>>>(hist + N_NODES, bsumoff, off, cursor);
    crd_wt<<<(F * F) / 256, 256, 0, stream>>>(W, Wt);
    crd_place<<<(N_EDGES + 255) / 256, 256, 0, stream>>>(src, dst, cursor, sorted);
    if (use_bf) {
        crd_xb<<<(int)(((size_t)N_NODES * F / 8) / 256), 256, 0, stream>>>(x, norms, xb);
        crd_gather_bf<<<N_PAD / 4, 256, 0, stream>>>(xb, sorted, off, norms, aggb);
    } else {
        crd_gather_f32<<<N_PAD / 4, 256, 0, stream>>>(x, sorted, off, norms, aggb);
    }
    crd_gemm<<<NWG, 256, 0, stream>>>(aggb, Wt, bias, out);
}

// Round 5
// 182.313 us; speedup vs baseline: 1.0754x; 1.0754x over previous
//
#include <hip/hip_runtime.h>
#include <hip/hip_bf16.h>

#define N_NODES 50000
#define N_PAD   50048   // 391 * 128
#define N_EDGES 150000
#define F 512
#define BN 128
#define NBLK 196        // ceil(50000/256)

typedef __attribute__((ext_vector_type(4))) float f32x4;
typedef __attribute__((ext_vector_type(4))) unsigned int u32x4;
typedef __attribute__((ext_vector_type(2))) unsigned int u32x2;

__device__ __forceinline__ unsigned short f2bf(float f) {
    unsigned int u = __float_as_uint(f);
    return (unsigned short)((u + 0x7fffu + ((u >> 16) & 1u)) >> 16);
}
__device__ __forceinline__ unsigned int pack2(float a, float b) {
    return (unsigned int)f2bf(a) | ((unsigned int)f2bf(b) << 16);
}
__device__ __forceinline__ void gload16(const void* g, void* l) {
    __builtin_amdgcn_global_load_lds(
        (const __attribute__((address_space(1))) unsigned int*)g,
        (__attribute__((address_space(3))) unsigned int*)l, 16, 0, 0);
}

// ---- degree histograms ----
__global__ void __launch_bounds__(256) crd_deg(const int* __restrict__ src,
                                               const int* __restrict__ dst,
                                               int* __restrict__ hist) {
    int e = blockIdx.x * 256 + threadIdx.x;
    if (e < N_EDGES) {
        atomicAdd(&hist[src[e]], 1);
        atomicAdd(&hist[N_NODES + dst[e]], 1);
    }
}

__global__ void __launch_bounds__(256) crd_norm(const int* __restrict__ hist,
                                                float* __restrict__ norms) {
    int i = blockIdx.x * 256 + threadIdx.x;
    if (i < 2 * N_NODES) {
        int d = hist[i];
        norms[i] = rsqrtf((float)(d > 0 ? d : 1));
    }
}

// ---- hierarchical exclusive scan of deg_in ----
__global__ void __launch_bounds__(256) crd_bsum(const int* __restrict__ hist_in,
                                                int* __restrict__ bsum) {
    __shared__ int s[256];
    int t = threadIdx.x;
    int i = blockIdx.x * 256 + t;
    s[t] = (i < N_NODES) ? hist_in[i] : 0;
    __syncthreads();
    #pragma unroll
    for (int o = 128; o > 0; o >>= 1) {
        if (t < o) s[t] += s[t + o];
        __syncthreads();
    }
    if (t == 0) bsum[blockIdx.x] = s[0];
}

__global__ void __launch_bounds__(256) crd_bscan(const int* __restrict__ bsum,
                                                 int* __restrict__ bsumoff) {
    __shared__ int s[256];
    int t = threadIdx.x;
    int v = (t < NBLK) ? bsum[t] : 0;
    s[t] = v;
    __syncthreads();
    #pragma unroll
    for (int d = 1; d < 256; d <<= 1) {
        int add = (t >= d) ? s[t - d] : 0;
        __syncthreads();
        s[t] += add;
        __syncthreads();
    }
    if (t < NBLK) bsumoff[t] = s[t] - v;
}

__global__ void __launch_bounds__(256) crd_escan(const int* __restrict__ hist_in,
                                                 const int* __restrict__ bsumoff,
                                                 int* __restrict__ off,
                                                 int* __restrict__ cursor) {
    __shared__ int s[256];
    int t = threadIdx.x;
    int i = blockIdx.x * 256 + t;
    int v = (i < N_NODES) ? hist_in[i] : 0;
    s[t] = v;
    __syncthreads();
    #pragma unroll
    for (int d = 1; d < 256; d <<= 1) {
        int add = (t >= d) ? s[t - d] : 0;
        __syncthreads();
        s[t] += add;
        __syncthreads();
    }
    int excl = s[t] - v + bsumoff[blockIdx.x];
    if (i < N_NODES) { off[i] = excl; cursor[i] = excl; }
    if (i == N_NODES - 1) off[N_NODES] = excl + v;
}

__global__ void __launch_bounds__(256) crd_place(const int* __restrict__ src,
                                                 const int* __restrict__ dst,
                                                 int* __restrict__ cursor,
                                                 int* __restrict__ sorted) {
    int e = blockIdx.x * 256 + threadIdx.x;
    if (e < N_EDGES) {
        int slot = atomicAdd(&cursor[dst[e]], 1);
        sorted[slot] = src[e];
    }
}

__global__ void __launch_bounds__(256) crd_wt(const float* __restrict__ W,
                                              unsigned short* __restrict__ Wt) {
    int idx = blockIdx.x * 256 + threadIdx.x;
    int n = idx >> 9, k = idx & 511;
    Wt[idx] = f2bf(W[k * F + n]);
}

// ---- xb = bf16(x * norm_src), 8 elems/thread ----
__global__ void __launch_bounds__(256) crd_xb(const float* __restrict__ x,
                                              const float* __restrict__ norms,
                                              unsigned short* __restrict__ xb) {
    int t = blockIdx.x * 256 + threadIdx.x;
    size_t i = (size_t)t * 8;
    float ns = norms[t >> 6];
    f32x4 v0 = *(const f32x4*)(x + i);
    f32x4 v1 = *(const f32x4*)(x + i + 4);
    v0 *= ns; v1 *= ns;
    u32x4 w;
    w.x = pack2(v0.x, v0.y); w.y = pack2(v0.z, v0.w);
    w.z = pack2(v1.x, v1.y); w.w = pack2(v1.z, v1.w);
    *(u32x4*)(xb + i) = w;
}

__device__ __forceinline__ void acc8(float* a, u32x4 v) {
    a[0] += __uint_as_float(v.x << 16); a[1] += __uint_as_float(v.x & 0xffff0000u);
    a[2] += __uint_as_float(v.y << 16); a[3] += __uint_as_float(v.y & 0xffff0000u);
    a[4] += __uint_as_float(v.z << 16); a[5] += __uint_as_float(v.z & 0xffff0000u);
    a[6] += __uint_as_float(v.w << 16); a[7] += __uint_as_float(v.w & 0xffff0000u);
}

// ---- one wave per dst node; xb already has norm_src folded in ----
__global__ void __launch_bounds__(256) crd_gather_bf(const unsigned short* __restrict__ xb,
                                                     const int* __restrict__ sorted,
                                                     const int* __restrict__ off,
                                                     const float* __restrict__ norms,
                                                     unsigned short* __restrict__ aggb) {
    int wid = (blockIdx.x * 256 + threadIdx.x) >> 6;
    int lane = threadIdx.x & 63;
    if (wid >= N_PAD) return;
    float a[8] = {0.f,0.f,0.f,0.f,0.f,0.f,0.f,0.f};
    float b[8] = {0.f,0.f,0.f,0.f,0.f,0.f,0.f,0.f};
    if (wid < N_NODES) {
        int e0 = off[wid], e1 = off[wid + 1];
        int e = e0;
        for (; e + 1 < e1; e += 2) {
            int s0 = sorted[e], s1 = sorted[e + 1];
            u32x4 v0 = *(const u32x4*)(xb + (size_t)s0 * F + lane * 8);
            u32x4 v1 = *(const u32x4*)(xb + (size_t)s1 * F + lane * 8);
            acc8(a, v0);
            acc8(b, v1);
        }
        if (e < e1) {
            u32x4 v0 = *(const u32x4*)(xb + (size_t)sorted[e] * F + lane * 8);
            acc8(a, v0);
        }
        float nd = norms[N_NODES + wid];
        #pragma unroll
        for (int j = 0; j < 8; ++j) a[j] = (a[j] + b[j]) * nd;
    }
    u32x4 w;
    w.x = pack2(a[0], a[1]); w.y = pack2(a[2], a[3]);
    w.z = pack2(a[4], a[5]); w.w = pack2(a[6], a[7]);
    *(u32x4*)(aggb + (size_t)wid * F + lane * 8) = w;
}

// ---- fallback (ws too small for xb): f32 x path ----
__global__ void __launch_bounds__(256) crd_gather_f32(const float* __restrict__ x,
                                                      const int* __restrict__ sorted,
                                                      const int* __restrict__ off,
                                                      const float* __restrict__ norms,
                                                      unsigned short* __restrict__ aggb) {
    int wid = (blockIdx.x * 256 + threadIdx.x) >> 6;
    int lane = threadIdx.x & 63;
    if (wid >= N_PAD) return;
    f32x4 a0 = {0.f,0.f,0.f,0.f}, a1 = a0;
    if (wid < N_NODES) {
        int e0 = off[wid], e1 = off[wid + 1];
        for (int e = e0; e < e1; ++e) {
            int s = sorted[e];
            float ns = norms[s];
            const f32x4* p = (const f32x4*)(x + (size_t)s * F);
            a0 += p[lane] * ns;
            a1 += p[64 + lane] * ns;
        }
        float nd = norms[N_NODES + wid];
        a0 *= nd; a1 *= nd;
    }
    unsigned short* row = aggb + (size_t)wid * F;
    u32x2 w0, w1;
    w0.x = pack2(a0.x, a0.y); w0.y = pack2(a0.z, a0.w);
    w1.x = pack2(a1.x, a1.y); w1.y = pack2(a1.z, a1.w);
    *(u32x2*)(row + lane * 4) = w0;
    *(u32x2*)(row + 256 + lane * 4) = w1;
}

// ---- out = relu(aggb @ W + b): B-panel-resident persistent GEMM ----
// 256 blocks (1/CU), 512 threads (8 waves, 4M x 2N; wave tile 32x64).
// LDS: whole B col-panel 512x128 bf16 = 128 KB (granule [k8g][n], k8g 0..63)
//    + 3 x 8 KB A-tile buffers (128 rows x 32 k, granule [k8][row], k8 0..3).
// Depth-2 prefetch: stage(s+2) -> compute(s) -> vmcnt(1) -> raw barrier.
// Fragment (16x16x32 bf16): lane l -> row/col = l&15, k = 8*(l>>4)+{0..7}.
__global__ void __launch_bounds__(512, 2) crd_gemm(const unsigned short* __restrict__ aggb,
                                                   const unsigned short* __restrict__ Wt,
                                                   const float* __restrict__ bias,
                                                   float* __restrict__ out) {
    __shared__ __align__(16) unsigned short lB[64 * 128 * 8];     // 128 KB
    __shared__ __align__(16) unsigned short lA[3][4 * 128 * 8];   // 3 x 8 KB
    const int tid = threadIdx.x;
    const int wave = tid >> 6, lane = tid & 63;
    const int g = lane >> 4, r = lane & 15;
    const int wm = wave >> 1;                  // 0..3: rows [wm*32, +32)
    const int wn = wave & 1;                   // 0..1: cols [wn*64, +64)
    const int nbase = (blockIdx.x & 3) * BN;   // col panel (constant per XCD)
    const int mgrp = blockIdx.x >> 2;          // 0..63
    const int njobs = (mgrp < 7) ? 7 : 6;      // 391 = 6*64 + 7 M-tiles
    const int total = njobs * 16;              // K-steps overall (BK=32)

    // ---- B panel preload: 16 rounds x 8 KB ----
    #pragma unroll
    for (int j = 0; j < 16; ++j) {
        int gg = j * 512 + tid;                // granule id = k8g*128 + n
        int k8g = gg >> 7, n = gg & 127;
        gload16(Wt + (size_t)(nbase + n) * F + k8g * 8,
                &lB[(size_t)(j * 512 + wave * 64) * 8]);
    }
    // ---- prologue: stage steps 0 and 1 ----
    {
        int k8 = tid >> 7, rw = tid & 127;
        const unsigned short* p = aggb + (size_t)(mgrp * 128 + rw) * F + k8 * 8;
        gload16(p, &lA[0][wave * 512]);
        gload16(p + 32, &lA[1][wave * 512]);   // ks=1 -> +32 elems
    }
    // bias per lane (col fixed for whole kernel)
    float bv[4];
    #pragma unroll
    for (int ni = 0; ni < 4; ++ni) bv[ni] = bias[nbase + wn * 64 + ni * 16 + r];

    __syncthreads();                           // full drain once

    f32x4 acc[2][4];
    #pragma unroll
    for (int mi = 0; mi < 2; ++mi)
        #pragma unroll
        for (int ni = 0; ni < 4; ++ni) acc[mi][ni] = (f32x4){0.f, 0.f, 0.f, 0.f};

    for (int s = 0; s < total; ++s) {
        int ks = s & 15;
        if (s + 2 < total) {                   // stage step s+2
            int s2 = s + 2;
            int rb2 = (mgrp + ((s2 >> 4) << 6)) * 128;
            int ks2 = s2 & 15;
            int k8 = tid >> 7, rw = tid & 127;
            gload16(aggb + (size_t)(rb2 + rw) * F + ks2 * 32 + k8 * 8,
                    &lA[s2 % 3][wave * 512]);
        }
        {   // compute step s from lA[s%3]
            const unsigned short* la = lA[s % 3];
            int k8g = ks * 4 + g;
            u32x4 af0 = *(const u32x4*)&la[(g * 128 + wm * 32 + r) * 8];
            u32x4 af1 = *(const u32x4*)&la[(g * 128 + wm * 32 + 16 + r) * 8];
            u32x4 bf0 = *(const u32x4*)&lB[(size_t)(k8g * 128 + wn * 64 + r) * 8];
            u32x4 bf1 = *(const u32x4*)&lB[(size_t)(k8g * 128 + wn * 64 + 16 + r) * 8];
            u32x4 bf2 = *(const u32x4*)&lB[(size_t)(k8g * 128 + wn * 64 + 32 + r) * 8];
            u32x4 bf3 = *(const u32x4*)&lB[(size_t)(k8g * 128 + wn * 64 + 48 + r) * 8];
            asm("v_mfma_f32_16x16x32_bf16 %0, %1, %2, %0" : "+v"(acc[0][0]) : "v"(af0), "v"(bf0));
            asm("v_mfma_f32_16x16x32_bf16 %0, %1, %2, %0" : "+v"(acc[0][1]) : "v"(af0), "v"(bf1));
            asm("v_mfma_f32_16x16x32_bf16 %0, %1, %2, %0" : "+v"(acc[0][2]) : "v"(af0), "v"(bf2));
            asm("v_mfma_f32_16x16x32_bf16 %0, %1, %2, %0" : "+v"(acc[0][3]) : "v"(af0), "v"(bf3));
            asm("v_mfma_f32_16x16x32_bf16 %0, %1, %2, %0" : "+v"(acc[1][0]) : "v"(af1), "v"(bf0));
            asm("v_mfma_f32_16x16x32_bf16 %0, %1, %2, %0" : "+v"(acc[1][1]) : "v"(af1), "v"(bf1));
            asm("v_mfma_f32_16x16x32_bf16 %0, %1, %2, %0" : "+v"(acc[1][2]) : "v"(af1), "v"(bf2));
            asm("v_mfma_f32_16x16x32_bf16 %0, %1, %2, %0" : "+v"(acc[1][3]) : "v"(af1), "v"(bf3));
        }
        // counted wait: keep newest stage in flight; ensure stage(s+1) landed
        if (s + 2 < total) asm volatile("s_waitcnt vmcnt(1)" ::: "memory");
        else               asm volatile("s_waitcnt vmcnt(0)" ::: "memory");
        __builtin_amdgcn_s_barrier();
        asm volatile("" ::: "memory");         // block load hoisting across barrier

        if (ks == 15) {                        // epilogue for finished M-tile
            int rowb = (mgrp + ((s >> 4) << 6)) * 128 + wm * 32;
            #pragma unroll
            for (int ni = 0; ni < 4; ++ni) {
                int col = nbase + wn * 64 + ni * 16 + r;
                #pragma unroll
                for (int mi = 0; mi < 2; ++mi) {
                    #pragma unroll
                    for (int jj = 0; jj < 4; ++jj) {
                        int row = rowb + mi * 16 + g * 4 + jj;
                        if (row < N_NODES) {
                            float v = acc[mi][ni][jj] + bv[ni];
                            out[(size_t)row * F + col] = v > 0.0f ? v : 0.0f;
                        }
                        acc[mi][ni][jj] = 0.0f;
                    }
                }
            }
        }
    }
}

extern "C" void kernel_launch(void* const* d_in, const int* in_sizes, int n_in,
                              void* d_out, int out_size, void* d_ws, size_t ws_size,
                              hipStream_t stream) {
    const float* x = (const float*)d_in[0];
    const int* src = (const int*)d_in[1];
    const int* dst = (const int*)d_in[2];
    const float* W = (const float*)d_in[3];
    const float* bias = (const float*)d_in[4];
    float* out = (float*)d_out;

    unsigned short* aggb = (unsigned short*)d_ws;               // N_PAD*F bf16
    unsigned short* Wt = aggb + (size_t)N_PAD * F;              // F*F bf16
    float* norms = (float*)(Wt + (size_t)F * F);                // 2N f32
    int* hist = (int*)(norms + 2 * N_NODES);                    // 2N int
    int* off = hist + 2 * N_NODES;                              // N+1 int
    int* cursor = off + N_NODES + 1;                            // N int
    int* sorted = cursor + N_NODES;                             // E int
    int* bsum = sorted + N_EDGES;                               // NBLK int
    int* bsumoff = bsum + NBLK;                                 // NBLK int
    char* endp = (char*)(bsumoff + NBLK);
    unsigned short* xb = (unsigned short*)(((uintptr_t)endp + 63) & ~(uintptr_t)63);
    size_t need_min = (size_t)(endp - (char*)d_ws);
    size_t need_bf = (size_t)((char*)(xb + (size_t)N_NODES * F) - (char*)d_ws);
    if (ws_size < need_min) {
        hipMemsetAsync(d_out, 0, (size_t)out_size * sizeof(float), stream);
        return;
    }
    const bool use_bf = (ws_size >= need_bf);

    hipMemsetAsync(hist, 0, 2 * N_NODES * sizeof(int), stream);
    crd_deg<<<(N_EDGES + 255) / 256, 256, 0, stream>>>(src, dst, hist);
    crd_norm<<<(2 * N_NODES + 255) / 256, 256, 0, stream>>>(hist, norms);
    crd_bsum<<<NBLK, 256, 0, stream>>>(hist + N_NODES, bsum);
    crd_bscan<<<1, 256, 0, stream>>>(bsum, bsumoff);
    crd_escan<<<NBLK, 256, 0, stream>>>(hist + N_NODES, bsumoff, off, cursor);
    crd_wt<<<(F * F) / 256, 256, 0, stream>>>(W, Wt);
    crd_place<<<(N_EDGES + 255) / 256, 256, 0, stream>>>(src, dst, cursor, sorted);
    if (use_bf) {
        crd_xb<<<(int)(((size_t)N_NODES * F / 8) / 256), 256, 0, stream>>>(x, norms, xb);
        crd_gather_bf<<<N_PAD / 4, 256, 0, stream>>>(xb, sorted, off, norms, aggb);
    } else {
        crd_gather_f32<<<N_PAD / 4, 256, 0, stream>>>(x, sorted, off, norms, aggb);
    }
    crd_gemm<<<256, 512, 0, stream>>>(aggb, Wt, bias, out);
}